// Round 5
// baseline (160.374 us; speedup 1.0000x reference)
//
#include <hip/hip_runtime.h>
#include <math.h>

#define HW 16384
#define CC 64
#define HID 128
#define EPSV 1e-5f
#define ROW 36     // padded LDS row for 32-pixel tiles
#define QROW 205   // padded per-pixel row for qkv staging (192 + 13, odd)
#define HDSTR 131072    // per-head stride: 32*32*16*8 floats

// q/k/v layout: [head][(hs*32+ws)*16 + sub][8], sub = (h&3)*4 + (w&3)

// ---------------- Kernel A: ln1 -> qkv -> q/k LN -> ws ----------------
__global__ __launch_bounds__(512) void k_ln_qkv(
    const float* __restrict__ x,
    const float* __restrict__ n1w, const float* __restrict__ n1b,
    const float* __restrict__ qkvw, const float* __restrict__ qkvb,
    const float* __restrict__ qnw, const float* __restrict__ qnb,
    const float* __restrict__ knw, const float* __restrict__ knb,
    float* __restrict__ qo, float* __restrict__ ko, float* __restrict__ vo)
{
    __shared__ __align__(16) float xs[CC][ROW];
    __shared__ __align__(16) float qk[32][QROW];
    __shared__ __align__(16) float mu1[32], rs1[32], muq[32], rsq[32], muk[32], rsk[32];

    const int t = threadIdx.x;
    const int pix0 = blockIdx.x * 32;   // 32 consecutive pixels, same image row

    // load x tile [c][px], one float4 per thread
    {
        const int c = t >> 3, pxq = (t & 7) * 4;
        *(float4*)&xs[c][pxq] = *(const float4*)(x + c * HW + pix0 + pxq);
    }
    __syncthreads();

    // ln1 stats: waves 0,1 each cover 16 px (4 partials x 16 px)
    if (t < 128) {
        const int px = ((t >> 6) << 4) + (t & 15);
        const int part = (t & 63) >> 4;
        float s = 0.f, ss = 0.f;
        #pragma unroll
        for (int i = 0; i < 16; ++i) { float v = xs[part * 16 + i][px]; s += v; ss += v * v; }
        s += __shfl_xor(s, 16); ss += __shfl_xor(ss, 16);
        s += __shfl_xor(s, 32); ss += __shfl_xor(ss, 32);
        if (part == 0) {
            float m = s * (1.f / CC);
            mu1[px] = m;
            rs1[px] = rsqrtf(ss * (1.f / CC) - m * m + EPSV);
        }
    }
    __syncthreads();

    // apply ln1 in-place, one float4 per thread
    {
        const int c = t >> 3, pxq = (t & 7) * 4;
        const float wgt = n1w[c], bia = n1b[c];
        float4 v = *(float4*)&xs[c][pxq];
        float4 m4 = *(float4*)&mu1[pxq];
        float4 r4 = *(float4*)&rs1[pxq];
        v.x = (v.x - m4.x) * r4.x * wgt + bia;
        v.y = (v.y - m4.y) * r4.y * wgt + bia;
        v.z = (v.z - m4.z) * r4.z * wgt + bia;
        v.w = (v.w - m4.w) * r4.w * wgt + bia;
        *(float4*)&xs[c][pxq] = v;
    }
    __syncthreads();

    // qkv matvec: thread = (og 0..31 -> 6 outs, pxg 0..15 -> 2 px)
    {
        const int o0 = (t >> 4) * 6;
        const int px0 = (t & 15) * 2;
        float a[6][2];
        #pragma unroll
        for (int j = 0; j < 6; ++j) {
            float b = qkvb[o0 + j];
            a[j][0] = b; a[j][1] = b;
        }
        for (int c = 0; c < CC; c += 4) {
            float2 xv[4];
            #pragma unroll
            for (int i = 0; i < 4; ++i) xv[i] = *(float2*)&xs[c + i][px0];
            #pragma unroll
            for (int j = 0; j < 6; ++j) {
                float4 wv = *(const float4*)(qkvw + (o0 + j) * CC + c);
                a[j][0] += wv.x * xv[0].x + wv.y * xv[1].x + wv.z * xv[2].x + wv.w * xv[3].x;
                a[j][1] += wv.x * xv[0].y + wv.y * xv[1].y + wv.z * xv[2].y + wv.w * xv[3].y;
            }
        }
        #pragma unroll
        for (int j = 0; j < 6; ++j) {
            qk[px0][o0 + j]     = a[j][0];
            qk[px0 + 1][o0 + j] = a[j][1];
        }
    }
    __syncthreads();

    // q stats (waves 0,1) and k stats (waves 2,3)
    if (t < 128) {
        const int px = ((t >> 6) << 4) + (t & 15);
        const int part = (t & 63) >> 4;
        float s = 0.f, ss = 0.f;
        #pragma unroll
        for (int i = 0; i < 16; ++i) { float v = qk[px][part * 16 + i]; s += v; ss += v * v; }
        s += __shfl_xor(s, 16); ss += __shfl_xor(ss, 16);
        s += __shfl_xor(s, 32); ss += __shfl_xor(ss, 32);
        if (part == 0) {
            float m = s * (1.f / CC);
            muq[px] = m;
            rsq[px] = rsqrtf(ss * (1.f / CC) - m * m + EPSV);
        }
    } else if (t < 256) {
        const int t2 = t - 128;
        const int px = ((t2 >> 6) << 4) + (t2 & 15);
        const int part = (t2 & 63) >> 4;
        float s = 0.f, ss = 0.f;
        #pragma unroll
        for (int i = 0; i < 16; ++i) { float v = qk[px][CC + part * 16 + i]; s += v; ss += v * v; }
        s += __shfl_xor(s, 16); ss += __shfl_xor(ss, 16);
        s += __shfl_xor(s, 32); ss += __shfl_xor(ss, 32);
        if (part == 0) {
            float m = s * (1.f / CC);
            muk[px] = m;
            rsk[px] = rsqrtf(ss * (1.f / CC) - m * m + EPSV);
        }
    }
    __syncthreads();

    // write q (LN), k (LN), v to interleaved subgrid layout — one pass, 512 threads
    {
        const int px = t >> 4;
        const int cg = t & 15;
        const int c = cg * 4;
        const int hd = cg >> 1;
        const int d4 = (cg & 1) * 4;
        const int pixel = pix0 + px;
        const int h = pixel >> 7, w = pixel & 127;
        const int pos = ((h >> 2) * 32 + (w >> 2)) * 16 + (h & 3) * 4 + (w & 3);
        const int gbase = hd * HDSTR + pos * 8 + d4;

        const float mq = muq[px], rq = rsq[px];
        float4 qv = *(float4*)&qk[px][c];
        float4 qw = *(const float4*)(qnw + c);
        float4 qb = *(const float4*)(qnb + c);
        qv.x = (qv.x - mq) * rq * qw.x + qb.x;
        qv.y = (qv.y - mq) * rq * qw.y + qb.y;
        qv.z = (qv.z - mq) * rq * qw.z + qb.z;
        qv.w = (qv.w - mq) * rq * qw.w + qb.w;
        *(float4*)(qo + gbase) = qv;

        const float mk = muk[px], rk = rsk[px];
        float4 kv = *(float4*)&qk[px][CC + c];
        float4 kw = *(const float4*)(knw + c);
        float4 kb = *(const float4*)(knb + c);
        kv.x = (kv.x - mk) * rk * kw.x + kb.x;
        kv.y = (kv.y - mk) * rk * kw.y + kb.y;
        kv.z = (kv.z - mk) * rk * kw.z + kb.z;
        kv.w = (kv.w - mk) * rk * kw.w + kb.w;
        *(float4*)(ko + gbase) = kv;

        float4 vv = *(float4*)&qk[px][2 * CC + c];
        *(float4*)(vo + gbase) = vv;
    }
}

// ---------------- Kernel B: subgrid NAT via LDS tiles ----------------
// grid = (band 0..3, subgrid 0..15, head 0..7); 256 threads = 8 rows x 32 cols
__global__ __launch_bounds__(256) void k_attn(
    const float* __restrict__ q, const float* __restrict__ k, const float* __restrict__ v,
    float* __restrict__ o)
{
    __shared__ __align__(16) float kt[4][15][33][2];
    __shared__ __align__(16) float vt[4][15][33][2];

    const int t = threadIdx.x;
    const int band = blockIdx.x;
    const int sub  = blockIdx.y;
    const int head = blockIdx.z;
    const int hs0 = band * 8;

    const float* kb = k + head * HDSTR;
    const float* vb = v + head * HDSTR;

    // stage k/v subgrid rows hs0-4 .. hs0+10 (clamped): 15 rows x 32 cols x 8 ch
    for (int idx = t; idx < 960; idx += 256) {
        const int row = idx >> 6;
        const int rem = idx & 63;
        const int ws = rem >> 1;
        const int dh = rem & 1;
        int gr = hs0 - 4 + row;
        gr = gr < 0 ? 0 : (gr > 31 ? 31 : gr);
        const int gaddr = ((gr * 32 + ws) * 16 + sub) * 8 + dh * 4;
        const float4 kv4 = *(const float4*)(kb + gaddr);
        const float4 vv4 = *(const float4*)(vb + gaddr);
        const int dp = dh * 2;
        kt[dp][row][ws][0] = kv4.x;     kt[dp][row][ws][1] = kv4.y;
        kt[dp + 1][row][ws][0] = kv4.z; kt[dp + 1][row][ws][1] = kv4.w;
        vt[dp][row][ws][0] = vv4.x;     vt[dp][row][ws][1] = vv4.y;
        vt[dp + 1][row][ws][0] = vv4.z; vt[dp + 1][row][ws][1] = vv4.w;
    }

    const int r = t >> 5;        // 0..7
    const int ws = t & 31;       // 0..31
    const int hs = hs0 + r;

    const float* qp = q + head * HDSTR + ((hs * 32 + ws) * 16 + sub) * 8;
    const float4 q0 = *(const float4*)qp;
    const float4 q1 = *(const float4*)(qp + 4);
    const float scale = 0.35355339059327373f;   // 8^-0.5

    __syncthreads();

    float m = -1e30f, l = 0.f;
    float a0 = 0.f, a1 = 0.f, a2 = 0.f, a3 = 0.f, a4 = 0.f, a5 = 0.f, a6 = 0.f, a7 = 0.f;

    #pragma unroll
    for (int i = 0; i < 8; ++i) {
        const int lr = r + i;                               // LDS row 0..14
        const bool vh = (unsigned)(hs + i - 4) < 32u;
        #pragma unroll
        for (int j = 0; j < 8; ++j) {
            const int cs = ws + j - 4;
            const bool valid = vh && ((unsigned)cs < 32u);
            const int cc = cs < 0 ? 0 : (cs > 31 ? 31 : cs);
            const float2 kA = *(const float2*)&kt[0][lr][cc][0];
            const float2 kB = *(const float2*)&kt[1][lr][cc][0];
            const float2 kC = *(const float2*)&kt[2][lr][cc][0];
            const float2 kD = *(const float2*)&kt[3][lr][cc][0];
            const float2 vA = *(const float2*)&vt[0][lr][cc][0];
            const float2 vB = *(const float2*)&vt[1][lr][cc][0];
            const float2 vC = *(const float2*)&vt[2][lr][cc][0];
            const float2 vD = *(const float2*)&vt[3][lr][cc][0];
            float s = q0.x * kA.x + q0.y * kA.y + q0.z * kB.x + q0.w * kB.y
                    + q1.x * kC.x + q1.y * kC.y + q1.z * kD.x + q1.w * kD.y;
            s *= scale;
            s = valid ? s : -INFINITY;
            const float mn = fmaxf(m, s);
            const float al = __expf(m - mn);
            const float p = __expf(s - mn);
            l = l * al + p;
            a0 = a0 * al + p * vA.x;  a1 = a1 * al + p * vA.y;
            a2 = a2 * al + p * vB.x;  a3 = a3 * al + p * vB.y;
            a4 = a4 * al + p * vC.x;  a5 = a5 * al + p * vC.y;
            a6 = a6 * al + p * vD.x;  a7 = a7 * al + p * vD.y;
            m = mn;
        }
    }

    const float inv = 1.f / l;
    const int a = sub >> 2, b = sub & 3;
    const int h = hs * 4 + a, w = ws * 4 + b;
    float* op = o + (h * 128 + w) * 64 + head * 8;
    float4 r0 = {a0 * inv, a1 * inv, a2 * inv, a3 * inv};
    float4 r1 = {a4 * inv, a5 * inv, a6 * inv, a7 * inv};
    *(float4*)op = r0;
    *(float4*)(op + 4) = r1;
}

// ---------------- Kernel C: proj+res -> ln2 -> fc1 -> mnLN+silu -> fc2 -> out ----------------
__global__ __launch_bounds__(512) void k_mlp(
    const float* __restrict__ x, const float* __restrict__ oatt,
    const float* __restrict__ pw, const float* __restrict__ pb,
    const float* __restrict__ g1,
    const float* __restrict__ n2w, const float* __restrict__ n2b,
    const float* __restrict__ f1w, const float* __restrict__ f1b,
    const float* __restrict__ mnw, const float* __restrict__ mnb,
    const float* __restrict__ f2w, const float* __restrict__ f2b,
    const float* __restrict__ g2,
    float* __restrict__ out)
{
    __shared__ __align__(16) float xres[CC][ROW];
    __shared__ __align__(16) float tb[CC][ROW];
    __shared__ __align__(16) float h1[HID][ROW];
    __shared__ __align__(16) float mu[32], rs[32];

    const int t = threadIdx.x;
    const int pix0 = blockIdx.x * 32;

    {
        const int c = t >> 3, pxq = (t & 7) * 4;
        *(float4*)&xres[c][pxq] = *(const float4*)(x + c * HW + pix0 + pxq);
    }
    {
        const int px = t >> 4, cg = (t & 15) * 4;
        float4 ov = *(const float4*)(oatt + (pix0 + px) * CC + cg);
        tb[cg][px] = ov.x; tb[cg + 1][px] = ov.y; tb[cg + 2][px] = ov.z; tb[cg + 3][px] = ov.w;
    }
    __syncthreads();

    // proj (64x64) + gamma1 residual into xres: 2 outs x 2 px per thread
    {
        const int o0 = (t >> 4) * 2;
        const int px0 = (t & 15) * 2;
        float a[2][2];
        #pragma unroll
        for (int j = 0; j < 2; ++j) { float b = pb[o0 + j]; a[j][0] = b; a[j][1] = b; }
        for (int c = 0; c < CC; c += 4) {
            float2 xv[4];
            #pragma unroll
            for (int i = 0; i < 4; ++i) xv[i] = *(float2*)&tb[c + i][px0];
            #pragma unroll
            for (int j = 0; j < 2; ++j) {
                float4 wv = *(const float4*)(pw + (o0 + j) * CC + c);
                a[j][0] += wv.x * xv[0].x + wv.y * xv[1].x + wv.z * xv[2].x + wv.w * xv[3].x;
                a[j][1] += wv.x * xv[0].y + wv.y * xv[1].y + wv.z * xv[2].y + wv.w * xv[3].y;
            }
        }
        #pragma unroll
        for (int j = 0; j < 2; ++j) {
            const float gg = g1[o0 + j];
            xres[o0 + j][px0]     += gg * a[j][0];
            xres[o0 + j][px0 + 1] += gg * a[j][1];
        }
    }
    __syncthreads();

    // ln2 stats (waves 0,1)
    if (t < 128) {
        const int px = ((t >> 6) << 4) + (t & 15);
        const int part = (t & 63) >> 4;
        float s = 0.f, ss = 0.f;
        #pragma unroll
        for (int i = 0; i < 16; ++i) { float v = xres[part * 16 + i][px]; s += v; ss += v * v; }
        s += __shfl_xor(s, 16); ss += __shfl_xor(ss, 16);
        s += __shfl_xor(s, 32); ss += __shfl_xor(ss, 32);
        if (part == 0) {
            float m = s * (1.f / CC);
            mu[px] = m;
            rs[px] = rsqrtf(ss * (1.f / CC) - m * m + EPSV);
        }
    }
    __syncthreads();

    // apply ln2 -> tb, one float4 per thread
    {
        const int c = t >> 3, pxq = (t & 7) * 4;
        const float wgt = n2w[c], bia = n2b[c];
        float4 v = *(float4*)&xres[c][pxq];
        float4 m4 = *(float4*)&mu[pxq];
        float4 r4 = *(float4*)&rs[pxq];
        v.x = (v.x - m4.x) * r4.x * wgt + bia;
        v.y = (v.y - m4.y) * r4.y * wgt + bia;
        v.z = (v.z - m4.z) * r4.z * wgt + bia;
        v.w = (v.w - m4.w) * r4.w * wgt + bia;
        *(float4*)&tb[c][pxq] = v;
    }
    __syncthreads();

    // fc1 (128x64) -> h1: 4 outs x 2 px per thread
    {
        const int o0 = (t >> 4) * 4;
        const int px0 = (t & 15) * 2;
        float a[4][2];
        #pragma unroll
        for (int j = 0; j < 4; ++j) { float b = f1b[o0 + j]; a[j][0] = b; a[j][1] = b; }
        for (int c = 0; c < CC; c += 4) {
            float2 xv[4];
            #pragma unroll
            for (int i = 0; i < 4; ++i) xv[i] = *(float2*)&tb[c + i][px0];
            #pragma unroll
            for (int j = 0; j < 4; ++j) {
                float4 wv = *(const float4*)(f1w + (o0 + j) * CC + c);
                a[j][0] += wv.x * xv[0].x + wv.y * xv[1].x + wv.z * xv[2].x + wv.w * xv[3].x;
                a[j][1] += wv.x * xv[0].y + wv.y * xv[1].y + wv.z * xv[2].y + wv.w * xv[3].y;
            }
        }
        #pragma unroll
        for (int j = 0; j < 4; ++j) {
            h1[o0 + j][px0]     = a[j][0];
            h1[o0 + j][px0 + 1] = a[j][1];
        }
    }
    __syncthreads();

    // mn stats over 128 channels (waves 0,1)
    if (t < 128) {
        const int px = ((t >> 6) << 4) + (t & 15);
        const int part = (t & 63) >> 4;
        float s = 0.f, ss = 0.f;
        #pragma unroll
        for (int i = 0; i < 32; ++i) { float v = h1[part * 32 + i][px]; s += v; ss += v * v; }
        s += __shfl_xor(s, 16); ss += __shfl_xor(ss, 16);
        s += __shfl_xor(s, 32); ss += __shfl_xor(ss, 32);
        if (part == 0) {
            float m = s * (1.f / HID);
            mu[px] = m;
            rs[px] = rsqrtf(ss * (1.f / HID) - m * m + EPSV);
        }
    }
    __syncthreads();

    // apply mn LN + silu in-place: 8 floats per thread
    {
        const int c = t >> 2, ph = (t & 3) * 8;
        const float wgt = mnw[c], bia = mnb[c];
        #pragma unroll
        for (int qq = 0; qq < 2; ++qq) {
            float4 v = *(float4*)&h1[c][ph + qq * 4];
            float4 m4 = *(float4*)&mu[ph + qq * 4];
            float4 r4 = *(float4*)&rs[ph + qq * 4];
            float hv;
            hv = (v.x - m4.x) * r4.x * wgt + bia; v.x = hv / (1.f + __expf(-hv));
            hv = (v.y - m4.y) * r4.y * wgt + bia; v.y = hv / (1.f + __expf(-hv));
            hv = (v.z - m4.z) * r4.z * wgt + bia; v.z = hv / (1.f + __expf(-hv));
            hv = (v.w - m4.w) * r4.w * wgt + bia; v.w = hv / (1.f + __expf(-hv));
            *(float4*)&h1[c][ph + qq * 4] = v;
        }
    }
    __syncthreads();

    // fc2 (64x128) + gamma2 residual -> out: 2 outs x 2 px per thread
    {
        const int o0 = (t >> 4) * 2;
        const int px0 = (t & 15) * 2;
        float a[2][2];
        #pragma unroll
        for (int j = 0; j < 2; ++j) { float b = f2b[o0 + j]; a[j][0] = b; a[j][1] = b; }
        for (int c = 0; c < HID; c += 4) {
            float2 xv[4];
            #pragma unroll
            for (int i = 0; i < 4; ++i) xv[i] = *(float2*)&h1[c + i][px0];
            #pragma unroll
            for (int j = 0; j < 2; ++j) {
                float4 wv = *(const float4*)(f2w + (o0 + j) * HID + c);
                a[j][0] += wv.x * xv[0].x + wv.y * xv[1].x + wv.z * xv[2].x + wv.w * xv[3].x;
                a[j][1] += wv.x * xv[0].y + wv.y * xv[1].y + wv.z * xv[2].y + wv.w * xv[3].y;
            }
        }
        #pragma unroll
        for (int j = 0; j < 2; ++j) {
            const float gg = g2[o0 + j];
            float2 xr = *(float2*)&xres[o0 + j][px0];
            float2 ov = {xr.x + gg * a[j][0], xr.y + gg * a[j][1]};
            *(float2*)(out + (o0 + j) * HW + pix0 + px0) = ov;
        }
    }
}

extern "C" void kernel_launch(void* const* d_in, const int* in_sizes, int n_in,
                              void* d_out, int out_size, void* d_ws, size_t ws_size,
                              hipStream_t stream) {
    (void)in_sizes; (void)n_in; (void)out_size; (void)ws_size;
    const float* x      = (const float*)d_in[0];
    const float* n1w    = (const float*)d_in[1];
    const float* n1b    = (const float*)d_in[2];
    const float* qkvw   = (const float*)d_in[3];
    const float* qkvb   = (const float*)d_in[4];
    const float* qnw    = (const float*)d_in[5];
    const float* qnb    = (const float*)d_in[6];
    const float* knw    = (const float*)d_in[7];
    const float* knb    = (const float*)d_in[8];
    const float* pw     = (const float*)d_in[9];
    const float* pb     = (const float*)d_in[10];
    const float* g1     = (const float*)d_in[11];
    const float* n2w    = (const float*)d_in[12];
    const float* n2b    = (const float*)d_in[13];
    const float* f1w    = (const float*)d_in[14];
    const float* f1b    = (const float*)d_in[15];
    const float* mnw    = (const float*)d_in[16];
    const float* mnb    = (const float*)d_in[17];
    const float* f2w    = (const float*)d_in[18];
    const float* f2b    = (const float*)d_in[19];
    const float* g2     = (const float*)d_in[20];
    float* out = (float*)d_out;

    float* ws = (float*)d_ws;
    const size_t CHW = (size_t)CC * HW;   // 1,048,576 floats
    float* qo   = ws;
    float* ko   = ws + CHW;
    float* vo   = ws + 2 * CHW;
    float* oatt = ws + 3 * CHW;

    k_ln_qkv<<<dim3(HW / 32), dim3(512), 0, stream>>>(
        x, n1w, n1b, qkvw, qkvb, qnw, qnb, knw, knb, qo, ko, vo);
    k_attn<<<dim3(4, 16, 8), dim3(256), 0, stream>>>(qo, ko, vo, oatt);
    k_mlp<<<dim3(HW / 32), dim3(512), 0, stream>>>(
        x, oatt, pw, pb, g1, n2w, n2b, f1w, f1b, mnw, mnb, f2w, f2b, g2, out);
}

// Round 6
// 149.411 us; speedup vs baseline: 1.0734x; 1.0734x over previous
//
#include <hip/hip_runtime.h>
#include <math.h>

#define HW 16384
#define CC 64
#define HID 128
#define EPSV 1e-5f
#define ROW 36     // padded LDS row for 32-pixel tiles (36%32=4 -> bank shift)
#define QROW 205   // padded per-pixel row for qkv staging (192 + 13, odd)
#define HDSTR 131072    // per-head stride: 32*32*16*8 floats

// q/k/v layout: [head][(hs*32+ws)*16 + sub][8], sub = (h&3)*4 + (w&3)

// ---------------- Kernel A: ln1 -> qkv -> q/k LN -> ws ----------------
__global__ __launch_bounds__(256) void k_ln_qkv(
    const float* __restrict__ x,
    const float* __restrict__ n1w, const float* __restrict__ n1b,
    const float* __restrict__ qkvw, const float* __restrict__ qkvb,
    const float* __restrict__ qnw, const float* __restrict__ qnb,
    const float* __restrict__ knw, const float* __restrict__ knb,
    float* __restrict__ qo, float* __restrict__ ko, float* __restrict__ vo)
{
    __shared__ __align__(16) float xs[CC][ROW];
    __shared__ __align__(16) float qk[32][QROW];
    __shared__ __align__(16) float mu1[32], rs1[32], muq[32], rsq[32], muk[32], rsk[32];

    const int t = threadIdx.x;
    const int pix0 = blockIdx.x * 32;   // 32 consecutive pixels, same image row

    // load x tile [c][px], 2 float4 per thread
    {
        const int c = t >> 2, pxq = (t & 3) * 8;
        *(float4*)&xs[c][pxq]     = *(const float4*)(x + c * HW + pix0 + pxq);
        *(float4*)&xs[c][pxq + 4] = *(const float4*)(x + c * HW + pix0 + pxq + 4);
    }
    __syncthreads();

    // ln1 stats: waves 0,1 each cover 16 px (4 partials x 16 px)
    if (t < 128) {
        const int px = ((t >> 6) << 4) + (t & 15);
        const int part = (t & 63) >> 4;
        float s = 0.f, ss = 0.f;
        #pragma unroll
        for (int i = 0; i < 16; ++i) { float v = xs[part * 16 + i][px]; s += v; ss += v * v; }
        s += __shfl_xor(s, 16); ss += __shfl_xor(ss, 16);
        s += __shfl_xor(s, 32); ss += __shfl_xor(ss, 32);
        if (part == 0) {
            float m = s * (1.f / CC);
            mu1[px] = m;
            rs1[px] = rsqrtf(ss * (1.f / CC) - m * m + EPSV);
        }
    }
    __syncthreads();

    // apply ln1 in-place
    {
        const int c = t >> 2, pxq = (t & 3) * 8;
        const float wgt = n1w[c], bia = n1b[c];
        #pragma unroll
        for (int hh = 0; hh < 2; ++hh) {
            float4 v = *(float4*)&xs[c][pxq + hh * 4];
            float4 m4 = *(float4*)&mu1[pxq + hh * 4];
            float4 r4 = *(float4*)&rs1[pxq + hh * 4];
            v.x = (v.x - m4.x) * r4.x * wgt + bia;
            v.y = (v.y - m4.y) * r4.y * wgt + bia;
            v.z = (v.z - m4.z) * r4.z * wgt + bia;
            v.w = (v.w - m4.w) * r4.w * wgt + bia;
            *(float4*)&xs[c][pxq + hh * 4] = v;
        }
    }
    __syncthreads();

    // qkv matvec: thread = (og 0..31 -> 6 outs, pxg 0..7 -> 4 px)
    {
        const int o0 = (t >> 3) * 6;
        const int px0 = (t & 7) * 4;
        float a[6][4];
        #pragma unroll
        for (int j = 0; j < 6; ++j) {
            float b = qkvb[o0 + j];
            a[j][0] = b; a[j][1] = b; a[j][2] = b; a[j][3] = b;
        }
        for (int c = 0; c < CC; c += 4) {
            float4 xv[4];
            #pragma unroll
            for (int i = 0; i < 4; ++i) xv[i] = *(float4*)&xs[c + i][px0];
            #pragma unroll
            for (int j = 0; j < 6; ++j) {
                float4 wv = *(const float4*)(qkvw + (o0 + j) * CC + c);
                #pragma unroll
                for (int pp = 0; pp < 4; ++pp) {
                    float xv0 = (&xv[0].x)[pp], xv1 = (&xv[1].x)[pp];
                    float xv2 = (&xv[2].x)[pp], xv3 = (&xv[3].x)[pp];
                    a[j][pp] += wv.x * xv0 + wv.y * xv1 + wv.z * xv2 + wv.w * xv3;
                }
            }
        }
        #pragma unroll
        for (int j = 0; j < 6; ++j) {
            #pragma unroll
            for (int pp = 0; pp < 4; ++pp) qk[px0 + pp][o0 + j] = a[j][pp];
        }
    }
    __syncthreads();

    // q stats (waves 0,1) and k stats (waves 2,3)
    if (t < 128) {
        const int px = ((t >> 6) << 4) + (t & 15);
        const int part = (t & 63) >> 4;
        float s = 0.f, ss = 0.f;
        #pragma unroll
        for (int i = 0; i < 16; ++i) { float v = qk[px][part * 16 + i]; s += v; ss += v * v; }
        s += __shfl_xor(s, 16); ss += __shfl_xor(ss, 16);
        s += __shfl_xor(s, 32); ss += __shfl_xor(ss, 32);
        if (part == 0) {
            float m = s * (1.f / CC);
            muq[px] = m;
            rsq[px] = rsqrtf(ss * (1.f / CC) - m * m + EPSV);
        }
    } else {
        const int t2 = t - 128;
        const int px = ((t2 >> 6) << 4) + (t2 & 15);
        const int part = (t2 & 63) >> 4;
        float s = 0.f, ss = 0.f;
        #pragma unroll
        for (int i = 0; i < 16; ++i) { float v = qk[px][CC + part * 16 + i]; s += v; ss += v * v; }
        s += __shfl_xor(s, 16); ss += __shfl_xor(ss, 16);
        s += __shfl_xor(s, 32); ss += __shfl_xor(ss, 32);
        if (part == 0) {
            float m = s * (1.f / CC);
            muk[px] = m;
            rsk[px] = rsqrtf(ss * (1.f / CC) - m * m + EPSV);
        }
    }
    __syncthreads();

    // write q (LN), k (LN), v to interleaved subgrid layout
    #pragma unroll
    for (int pass = 0; pass < 2; ++pass) {
        const int px = (t >> 4) + pass * 16;
        const int cg = t & 15;
        const int c = cg * 4;
        const int hd = cg >> 1;
        const int d4 = (cg & 1) * 4;
        const int pixel = pix0 + px;
        const int h = pixel >> 7, w = pixel & 127;
        const int pos = ((h >> 2) * 32 + (w >> 2)) * 16 + (h & 3) * 4 + (w & 3);
        const int gbase = hd * HDSTR + pos * 8 + d4;

        const float mq = muq[px], rq = rsq[px];
        float4 qv = *(float4*)&qk[px][c];
        float4 qw = *(const float4*)(qnw + c);
        float4 qb = *(const float4*)(qnb + c);
        qv.x = (qv.x - mq) * rq * qw.x + qb.x;
        qv.y = (qv.y - mq) * rq * qw.y + qb.y;
        qv.z = (qv.z - mq) * rq * qw.z + qb.z;
        qv.w = (qv.w - mq) * rq * qw.w + qb.w;
        *(float4*)(qo + gbase) = qv;

        const float mk = muk[px], rk = rsk[px];
        float4 kv = *(float4*)&qk[px][CC + c];
        float4 kw = *(const float4*)(knw + c);
        float4 kb = *(const float4*)(knb + c);
        kv.x = (kv.x - mk) * rk * kw.x + kb.x;
        kv.y = (kv.y - mk) * rk * kw.y + kb.y;
        kv.z = (kv.z - mk) * rk * kw.z + kb.z;
        kv.w = (kv.w - mk) * rk * kw.w + kb.w;
        *(float4*)(ko + gbase) = kv;

        float4 vv = *(float4*)&qk[px][2 * CC + c];
        *(float4*)(vo + gbase) = vv;
    }
}

// ---------------- Kernel B: subgrid NAT via LDS tiles ----------------
// grid = (band 0..3, subgrid 0..15, head 0..7); 256 threads = 8 rows x 32 cols
__global__ __launch_bounds__(256) void k_attn(
    const float* __restrict__ q, const float* __restrict__ k, const float* __restrict__ v,
    float* __restrict__ o)
{
    __shared__ __align__(16) float kt[4][15][33][2];
    __shared__ __align__(16) float vt[4][15][33][2];

    const int t = threadIdx.x;
    const int band = blockIdx.x;
    const int sub  = blockIdx.y;
    const int head = blockIdx.z;
    const int hs0 = band * 8;

    const float* kb = k + head * HDSTR;
    const float* vb = v + head * HDSTR;

    // stage k/v subgrid rows hs0-4 .. hs0+10 (clamped): 15 rows x 32 cols x 8 ch
    for (int idx = t; idx < 960; idx += 256) {
        const int row = idx >> 6;
        const int rem = idx & 63;
        const int ws = rem >> 1;
        const int dh = rem & 1;
        int gr = hs0 - 4 + row;
        gr = gr < 0 ? 0 : (gr > 31 ? 31 : gr);
        const int gaddr = ((gr * 32 + ws) * 16 + sub) * 8 + dh * 4;
        const float4 kv4 = *(const float4*)(kb + gaddr);
        const float4 vv4 = *(const float4*)(vb + gaddr);
        const int dp = dh * 2;
        kt[dp][row][ws][0] = kv4.x;     kt[dp][row][ws][1] = kv4.y;
        kt[dp + 1][row][ws][0] = kv4.z; kt[dp + 1][row][ws][1] = kv4.w;
        vt[dp][row][ws][0] = vv4.x;     vt[dp][row][ws][1] = vv4.y;
        vt[dp + 1][row][ws][0] = vv4.z; vt[dp + 1][row][ws][1] = vv4.w;
    }

    const int r = t >> 5;        // 0..7
    const int ws = t & 31;       // 0..31
    const int hs = hs0 + r;

    const float* qp = q + head * HDSTR + ((hs * 32 + ws) * 16 + sub) * 8;
    const float4 q0 = *(const float4*)qp;
    const float4 q1 = *(const float4*)(qp + 4);
    const float scale = 0.35355339059327373f;   // 8^-0.5

    __syncthreads();

    float m = -1e30f, l = 0.f;
    float a0 = 0.f, a1 = 0.f, a2 = 0.f, a3 = 0.f, a4 = 0.f, a5 = 0.f, a6 = 0.f, a7 = 0.f;

    #pragma unroll
    for (int i = 0; i < 8; ++i) {
        const int lr = r + i;                               // LDS row 0..14
        const bool vh = (unsigned)(hs + i - 4) < 32u;
        #pragma unroll
        for (int j = 0; j < 8; ++j) {
            const int cs = ws + j - 4;
            const bool valid = vh && ((unsigned)cs < 32u);
            const int cc = cs < 0 ? 0 : (cs > 31 ? 31 : cs);
            const float2 kA = *(const float2*)&kt[0][lr][cc][0];
            const float2 kB = *(const float2*)&kt[1][lr][cc][0];
            const float2 kC = *(const float2*)&kt[2][lr][cc][0];
            const float2 kD = *(const float2*)&kt[3][lr][cc][0];
            const float2 vA = *(const float2*)&vt[0][lr][cc][0];
            const float2 vB = *(const float2*)&vt[1][lr][cc][0];
            const float2 vC = *(const float2*)&vt[2][lr][cc][0];
            const float2 vD = *(const float2*)&vt[3][lr][cc][0];
            float s = q0.x * kA.x + q0.y * kA.y + q0.z * kB.x + q0.w * kB.y
                    + q1.x * kC.x + q1.y * kC.y + q1.z * kD.x + q1.w * kD.y;
            s *= scale;
            s = valid ? s : -INFINITY;
            const float mn = fmaxf(m, s);
            const float al = __expf(m - mn);
            const float p = __expf(s - mn);
            l = l * al + p;
            a0 = a0 * al + p * vA.x;  a1 = a1 * al + p * vA.y;
            a2 = a2 * al + p * vB.x;  a3 = a3 * al + p * vB.y;
            a4 = a4 * al + p * vC.x;  a5 = a5 * al + p * vC.y;
            a6 = a6 * al + p * vD.x;  a7 = a7 * al + p * vD.y;
            m = mn;
        }
    }

    const float inv = 1.f / l;
    const int a = sub >> 2, b = sub & 3;
    const int h = hs * 4 + a, w = ws * 4 + b;
    float* op = o + (h * 128 + w) * 64 + head * 8;
    float4 r0 = {a0 * inv, a1 * inv, a2 * inv, a3 * inv};
    float4 r1 = {a4 * inv, a5 * inv, a6 * inv, a7 * inv};
    *(float4*)op = r0;
    *(float4*)(op + 4) = r1;
}

// ---------------- Kernel C: proj+res -> ln2 -> fc1 -> mnLN+silu -> fc2 -> out ----------------
__global__ __launch_bounds__(256) void k_mlp(
    const float* __restrict__ x, const float* __restrict__ oatt,
    const float* __restrict__ pw, const float* __restrict__ pb,
    const float* __restrict__ g1,
    const float* __restrict__ n2w, const float* __restrict__ n2b,
    const float* __restrict__ f1w, const float* __restrict__ f1b,
    const float* __restrict__ mnw, const float* __restrict__ mnb,
    const float* __restrict__ f2w, const float* __restrict__ f2b,
    const float* __restrict__ g2,
    float* __restrict__ out)
{
    __shared__ __align__(16) float xres[CC][ROW];
    __shared__ __align__(16) float tb[CC][ROW];
    __shared__ __align__(16) float h1[HID][ROW];
    __shared__ __align__(16) float mu[32], rs[32];

    const int t = threadIdx.x;
    const int pix0 = blockIdx.x * 32;

    {
        const int c = t >> 2, pxq = (t & 3) * 8;
        *(float4*)&xres[c][pxq]     = *(const float4*)(x + c * HW + pix0 + pxq);
        *(float4*)&xres[c][pxq + 4] = *(const float4*)(x + c * HW + pix0 + pxq + 4);
    }
    #pragma unroll
    for (int pass = 0; pass < 2; ++pass) {
        const int px = (t >> 4) + pass * 16, cg = (t & 15) * 4;
        float4 ov = *(const float4*)(oatt + (pix0 + px) * CC + cg);
        tb[cg][px] = ov.x; tb[cg + 1][px] = ov.y; tb[cg + 2][px] = ov.z; tb[cg + 3][px] = ov.w;
    }
    __syncthreads();

    // proj (64x64) + gamma1 residual into xres
    {
        const int o0 = (t >> 3) * 2;
        const int px0 = (t & 7) * 4;
        float a[2][4];
        #pragma unroll
        for (int j = 0; j < 2; ++j) {
            float b = pb[o0 + j];
            a[j][0] = b; a[j][1] = b; a[j][2] = b; a[j][3] = b;
        }
        for (int c = 0; c < CC; c += 4) {
            float4 xv[4];
            #pragma unroll
            for (int i = 0; i < 4; ++i) xv[i] = *(float4*)&tb[c + i][px0];
            #pragma unroll
            for (int j = 0; j < 2; ++j) {
                float4 wv = *(const float4*)(pw + (o0 + j) * CC + c);
                #pragma unroll
                for (int pp = 0; pp < 4; ++pp) {
                    a[j][pp] += wv.x * (&xv[0].x)[pp] + wv.y * (&xv[1].x)[pp]
                              + wv.z * (&xv[2].x)[pp] + wv.w * (&xv[3].x)[pp];
                }
            }
        }
        #pragma unroll
        for (int j = 0; j < 2; ++j) {
            const float gg = g1[o0 + j];
            #pragma unroll
            for (int pp = 0; pp < 4; ++pp) xres[o0 + j][px0 + pp] += gg * a[j][pp];
        }
    }
    __syncthreads();

    // ln2 stats (waves 0,1)
    if (t < 128) {
        const int px = ((t >> 6) << 4) + (t & 15);
        const int part = (t & 63) >> 4;
        float s = 0.f, ss = 0.f;
        #pragma unroll
        for (int i = 0; i < 16; ++i) { float v = xres[part * 16 + i][px]; s += v; ss += v * v; }
        s += __shfl_xor(s, 16); ss += __shfl_xor(ss, 16);
        s += __shfl_xor(s, 32); ss += __shfl_xor(ss, 32);
        if (part == 0) {
            float m = s * (1.f / CC);
            mu[px] = m;
            rs[px] = rsqrtf(ss * (1.f / CC) - m * m + EPSV);
        }
    }
    __syncthreads();

    // apply ln2 -> tb
    {
        const int c = t >> 2, pxq = (t & 3) * 8;
        const float wgt = n2w[c], bia = n2b[c];
        #pragma unroll
        for (int hh = 0; hh < 2; ++hh) {
            float4 v = *(float4*)&xres[c][pxq + hh * 4];
            float4 m4 = *(float4*)&mu[pxq + hh * 4];
            float4 r4 = *(float4*)&rs[pxq + hh * 4];
            v.x = (v.x - m4.x) * r4.x * wgt + bia;
            v.y = (v.y - m4.y) * r4.y * wgt + bia;
            v.z = (v.z - m4.z) * r4.z * wgt + bia;
            v.w = (v.w - m4.w) * r4.w * wgt + bia;
            *(float4*)&tb[c][pxq + hh * 4] = v;
        }
    }
    __syncthreads();

    // fc1 (128x64) -> h1
    {
        const int o0 = (t >> 3) * 4;
        const int px0 = (t & 7) * 4;
        float a[4][4];
        #pragma unroll
        for (int j = 0; j < 4; ++j) {
            float b = f1b[o0 + j];
            a[j][0] = b; a[j][1] = b; a[j][2] = b; a[j][3] = b;
        }
        for (int c = 0; c < CC; c += 4) {
            float4 xv[4];
            #pragma unroll
            for (int i = 0; i < 4; ++i) xv[i] = *(float4*)&tb[c + i][px0];
            #pragma unroll
            for (int j = 0; j < 4; ++j) {
                float4 wv = *(const float4*)(f1w + (o0 + j) * CC + c);
                #pragma unroll
                for (int pp = 0; pp < 4; ++pp) {
                    a[j][pp] += wv.x * (&xv[0].x)[pp] + wv.y * (&xv[1].x)[pp]
                              + wv.z * (&xv[2].x)[pp] + wv.w * (&xv[3].x)[pp];
                }
            }
        }
        #pragma unroll
        for (int j = 0; j < 4; ++j) {
            #pragma unroll
            for (int pp = 0; pp < 4; ++pp) h1[o0 + j][px0 + pp] = a[j][pp];
        }
    }
    __syncthreads();

    // mn stats over 128 channels (waves 0,1)
    if (t < 128) {
        const int px = ((t >> 6) << 4) + (t & 15);
        const int part = (t & 63) >> 4;
        float s = 0.f, ss = 0.f;
        #pragma unroll
        for (int i = 0; i < 32; ++i) { float v = h1[part * 32 + i][px]; s += v; ss += v * v; }
        s += __shfl_xor(s, 16); ss += __shfl_xor(ss, 16);
        s += __shfl_xor(s, 32); ss += __shfl_xor(ss, 32);
        if (part == 0) {
            float m = s * (1.f / HID);
            mu[px] = m;
            rs[px] = rsqrtf(ss * (1.f / HID) - m * m + EPSV);
        }
    }
    __syncthreads();

    // apply mn LN + silu in-place
    {
        const int c = t >> 1, ph = (t & 1) * 16;
        const float wgt = mnw[c], bia = mnb[c];
        #pragma unroll
        for (int qq = 0; qq < 4; ++qq) {
            float4 v = *(float4*)&h1[c][ph + qq * 4];
            float4 m4 = *(float4*)&mu[ph + qq * 4];
            float4 r4 = *(float4*)&rs[ph + qq * 4];
            float hv;
            hv = (v.x - m4.x) * r4.x * wgt + bia; v.x = hv / (1.f + __expf(-hv));
            hv = (v.y - m4.y) * r4.y * wgt + bia; v.y = hv / (1.f + __expf(-hv));
            hv = (v.z - m4.z) * r4.z * wgt + bia; v.z = hv / (1.f + __expf(-hv));
            hv = (v.w - m4.w) * r4.w * wgt + bia; v.w = hv / (1.f + __expf(-hv));
            *(float4*)&h1[c][ph + qq * 4] = v;
        }
    }
    __syncthreads();

    // fc2 (64x128) + gamma2 residual -> out (float4 stores)
    {
        const int o0 = (t >> 3) * 2;
        const int px0 = (t & 7) * 4;
        float a[2][4];
        #pragma unroll
        for (int j = 0; j < 2; ++j) {
            float b = f2b[o0 + j];
            a[j][0] = b; a[j][1] = b; a[j][2] = b; a[j][3] = b;
        }
        for (int c = 0; c < HID; c += 4) {
            float4 xv[4];
            #pragma unroll
            for (int i = 0; i < 4; ++i) xv[i] = *(float4*)&h1[c + i][px0];
            #pragma unroll
            for (int j = 0; j < 2; ++j) {
                float4 wv = *(const float4*)(f2w + (o0 + j) * HID + c);
                #pragma unroll
                for (int pp = 0; pp < 4; ++pp) {
                    a[j][pp] += wv.x * (&xv[0].x)[pp] + wv.y * (&xv[1].x)[pp]
                              + wv.z * (&xv[2].x)[pp] + wv.w * (&xv[3].x)[pp];
                }
            }
        }
        #pragma unroll
        for (int j = 0; j < 2; ++j) {
            const float gg = g2[o0 + j];
            float4 xr = *(float4*)&xres[o0 + j][px0];
            float4 ov = {xr.x + gg * a[j][0], xr.y + gg * a[j][1],
                         xr.z + gg * a[j][2], xr.w + gg * a[j][3]};
            *(float4*)(out + (o0 + j) * HW + pix0 + px0) = ov;
        }
    }
}

extern "C" void kernel_launch(void* const* d_in, const int* in_sizes, int n_in,
                              void* d_out, int out_size, void* d_ws, size_t ws_size,
                              hipStream_t stream) {
    (void)in_sizes; (void)n_in; (void)out_size; (void)ws_size;
    const float* x      = (const float*)d_in[0];
    const float* n1w    = (const float*)d_in[1];
    const float* n1b    = (const float*)d_in[2];
    const float* qkvw   = (const float*)d_in[3];
    const float* qkvb   = (const float*)d_in[4];
    const float* qnw    = (const float*)d_in[5];
    const float* qnb    = (const float*)d_in[6];
    const float* knw    = (const float*)d_in[7];
    const float* knb    = (const float*)d_in[8];
    const float* pw     = (const float*)d_in[9];
    const float* pb     = (const float*)d_in[10];
    const float* g1     = (const float*)d_in[11];
    const float* n2w    = (const float*)d_in[12];
    const float* n2b    = (const float*)d_in[13];
    const float* f1w    = (const float*)d_in[14];
    const float* f1b    = (const float*)d_in[15];
    const float* mnw    = (const float*)d_in[16];
    const float* mnb    = (const float*)d_in[17];
    const float* f2w    = (const float*)d_in[18];
    const float* f2b    = (const float*)d_in[19];
    const float* g2     = (const float*)d_in[20];
    float* out = (float*)d_out;

    float* ws = (float*)d_ws;
    const size_t CHW = (size_t)CC * HW;   // 1,048,576 floats
    float* qo   = ws;
    float* ko   = ws + CHW;
    float* vo   = ws + 2 * CHW;
    float* oatt = ws + 3 * CHW;

    k_ln_qkv<<<dim3(HW / 32), dim3(256), 0, stream>>>(
        x, n1w, n1b, qkvw, qkvb, qnw, qnb, knw, knb, qo, ko, vo);
    k_attn<<<dim3(4, 16, 8), dim3(256), 0, stream>>>(qo, ko, vo, oatt);
    k_mlp<<<dim3(HW / 32), dim3(256), 0, stream>>>(
        x, oatt, pw, pb, g1, n2w, n2b, f1w, f1b, mnw, mnb, f2w, f2b, g2, out);
}